// Round 1
// baseline (377.270 us; speedup 1.0000x reference)
//
#include <hip/hip_runtime.h>
#include <hip/hip_bf16.h>

typedef unsigned short u16;
typedef __attribute__((ext_vector_type(8))) __bf16 bf16x8;
typedef __attribute__((ext_vector_type(4))) float f32x4;

#define CC 1024
#define LL 4096
#define NB 8

__device__ __forceinline__ u16 f2bf(float f) {
  union { float f; unsigned u; } v; v.f = f;
  unsigned u = v.u;
  return (u16)((u + 0x7fffu + ((u >> 16) & 1u)) >> 16);
}

__device__ __forceinline__ void gload_lds16(const void* g, void* l) {
  __builtin_amdgcn_global_load_lds(
      (const __attribute__((address_space(1))) void*)g,
      (__attribute__((address_space(3))) void*)l, 16, 0, 0);
}

// ---------------------------------------------------------------------------
// Fused depthwise conv (K=7, pad=3) producing q,k row-major [b,c,l] bf16 and
// v transposed [b,l,c] bf16. Tile: 64 channels x 64 positions per block.
// ---------------------------------------------------------------------------
__global__ __launch_bounds__(256) void dwconv_qkv(
    const float* __restrict__ x, const float* __restrict__ qw,
    const float* __restrict__ kw, const float* __restrict__ vw,
    u16* __restrict__ qo, u16* __restrict__ ko, u16* __restrict__ vto)
{
  __shared__ float xs[64][72];   // 64 rows x 70 cols used (halo 3+3), pad to 72
  __shared__ u16 vs[64][66];     // v tile transposed staging [l][c]
  const int t  = threadIdx.x;
  const int l0 = blockIdx.x << 6;
  const int c0 = blockIdx.y << 6;
  const int b  = blockIdx.z;
  const float* xb = x + ((size_t)(b * CC + c0)) * LL;

  for (int idx = t; idx < 64 * 70; idx += 256) {
    int r = idx / 70, col = idx - r * 70;
    int gl = l0 - 3 + col;
    float v = 0.f;
    if ((unsigned)gl < (unsigned)LL) v = xb[(size_t)r * LL + gl];
    xs[r][col] = v;
  }
  __syncthreads();

  const int cc  = t >> 2;          // channel within tile
  const int li0 = (t & 3) << 4;    // 16 positions per thread
  const int c   = c0 + cc;
  float wq[7], wk[7], wv[7];
#pragma unroll
  for (int j = 0; j < 7; ++j) {
    wq[j] = qw[c * 7 + j]; wk[j] = kw[c * 7 + j]; wv[j] = vw[c * 7 + j];
  }
  alignas(16) u16 qv[16], kv[16];
#pragma unroll
  for (int li = 0; li < 16; ++li) {
    float aq = 0.f, ak = 0.f, av = 0.f;
#pragma unroll
    for (int j = 0; j < 7; ++j) {
      float xv = xs[cc][li0 + li + j];
      aq = fmaf(xv, wq[j], aq);
      ak = fmaf(xv, wk[j], ak);
      av = fmaf(xv, wv[j], av);
    }
    qv[li] = f2bf(aq);
    kv[li] = f2bf(ak);
    vs[li0 + li][cc] = f2bf(av);
  }
  size_t qoff = ((size_t)(b * CC + c)) * LL + l0 + li0;
  *(uint4*)(qo + qoff)     = ((const uint4*)qv)[0];
  *(uint4*)(qo + qoff + 8) = ((const uint4*)qv)[1];
  *(uint4*)(ko + qoff)     = ((const uint4*)kv)[0];
  *(uint4*)(ko + qoff + 8) = ((const uint4*)kv)[1];

  __syncthreads();
  const int ll = t >> 2;
  const int cg = (t & 3) << 4;
  alignas(16) u16 vr[16];
#pragma unroll
  for (int j = 0; j < 16; ++j) vr[j] = vs[ll][cg + j];
  size_t voff = ((size_t)(b * LL + l0 + ll)) * CC + c0 + cg;
  *(uint4*)(vto + voff)     = ((const uint4*)vr)[0];
  *(uint4*)(vto + voff + 8) = ((const uint4*)vr)[1];
}

// ---------------------------------------------------------------------------
// NT bf16 GEMM: C[m][n] = sum_k A[m][k] * B[n][k]; A,B row-major K-contiguous.
// 128x128 tile, BK=64, 4 waves (2x2 of 64x64), mfma_f32_16x16x32_bf16.
// global_load_lds (16B) staging with XOR-swizzled source so swizzled
// ds_read_b128 fragment reads are ~conflict-free. m97-class structure.
// ---------------------------------------------------------------------------
__global__ __launch_bounds__(256) void gemm_nt(
    const u16* __restrict__ A, int lda, size_t sA,
    const u16* __restrict__ B, int ldb, size_t sB,
    float* __restrict__ C, int ldc, size_t sC, int K)
{
  __shared__ u16 As[8192];  // 128 x 64 bf16 (swizzled within rows)
  __shared__ u16 Bs[8192];
  const int t    = threadIdx.x;
  const int lane = t & 63, wave = t >> 6;
  const int WR = wave >> 1, WC = wave & 1;
  const int bm = blockIdx.y << 7, bn = blockIdx.x << 7;
  const size_t bz = blockIdx.z;
  const u16* Ab = A + bz * sA;
  const u16* Bb = B + bz * sB;

  // Staging addresses. Chunk = 1KB = 8 rows of 64 bf16; wave w owns chunks
  // 4w..4w+3. Lane l -> row = chunk*8 + (l>>3), source col block swizzled.
  const int srow = lane >> 3;                       // 0..7
  const int scol = ((lane & 7) ^ srow) << 3;        // swizzled elem col 0..56
  const u16* aSrc[4]; const u16* bSrc[4];
  u16* aDst[4]; u16* bDst[4];
#pragma unroll
  for (int i = 0; i < 4; ++i) {
    int chunk = wave * 4 + i;
    int row = chunk * 8 + srow;
    aSrc[i] = Ab + (size_t)(bm + row) * lda + scol;
    bSrc[i] = Bb + (size_t)(bn + row) * ldb + scol;
    aDst[i] = As + chunk * 512;
    bDst[i] = Bs + chunk * 512;
  }

  const int r15 = lane & 15;
  const int kq  = lane >> 4;   // 0..3
  const int swz = r15 & 7;

  f32x4 acc[4][4];
#pragma unroll
  for (int i = 0; i < 4; ++i)
#pragma unroll
    for (int j = 0; j < 4; ++j) acc[i][j] = f32x4{0.f, 0.f, 0.f, 0.f};

  int aOff[4], bOff[4];
#pragma unroll
  for (int mi = 0; mi < 4; ++mi) aOff[mi] = (WR * 64 + mi * 16 + r15) * 128;
#pragma unroll
  for (int ni = 0; ni < 4; ++ni) bOff[ni] = (WC * 64 + ni * 16 + r15) * 128;

  const int nk = K >> 6;
  for (int kt = 0; kt < nk; ++kt) {
    const int k0 = kt << 6;
#pragma unroll
    for (int i = 0; i < 4; ++i) {
      gload_lds16(aSrc[i] + k0, aDst[i]);
      gload_lds16(bSrc[i] + k0, bDst[i]);
    }
    __syncthreads();   // drains vmcnt before any wave reads LDS
#pragma unroll
    for (int ks = 0; ks < 2; ++ks) {
      const int u = (ks << 2) + kq;
      const int uo = (u ^ swz) << 4;
      bf16x8 af[4], bfr[4];
#pragma unroll
      for (int mi = 0; mi < 4; ++mi)
        af[mi] = *(const bf16x8*)((const char*)As + aOff[mi] + uo);
#pragma unroll
      for (int ni = 0; ni < 4; ++ni)
        bfr[ni] = *(const bf16x8*)((const char*)Bs + bOff[ni] + uo);
#pragma unroll
      for (int mi = 0; mi < 4; ++mi)
#pragma unroll
        for (int ni = 0; ni < 4; ++ni)
          acc[mi][ni] = __builtin_amdgcn_mfma_f32_16x16x32_bf16(
              af[mi], bfr[ni], acc[mi][ni], 0, 0, 0);
    }
    __syncthreads();   // before next-iter staging overwrites LDS
  }

  float* Cb = C + bz * sC;
  const int row0 = bm + WR * 64 + kq * 4;
  const int col0 = bn + WC * 64 + r15;
#pragma unroll
  for (int mi = 0; mi < 4; ++mi)
#pragma unroll
    for (int ni = 0; ni < 4; ++ni) {
      const int r   = row0 + mi * 16;
      const int col = col0 + ni * 16;
#pragma unroll
      for (int rr = 0; rr < 4; ++rr)
        Cb[(size_t)(r + rr) * ldc + col] = acc[mi][ni][rr];
    }
}

// ---------------------------------------------------------------------------
// Row softmax over fp32 [8192][1024] with 1/sqrt(C) scaling; writes bf16 attn
// in place at the start of each fp32 row (row stride stays 4096 B = 2048 u16).
// ---------------------------------------------------------------------------
__global__ __launch_bounds__(256) void softmax_rows(float* __restrict__ score)
{
  __shared__ float rmax[4], rsum[4];
  const int t = threadIdx.x;
  const int lane = t & 63, wv = t >> 6;
  float* sp = score + ((size_t)blockIdx.x << 10);
  float4 v = ((const float4*)sp)[t];
  const float scale = 0.03125f;   // 1/sqrt(1024)
  float a0 = v.x * scale, a1 = v.y * scale, a2 = v.z * scale, a3 = v.w * scale;
  float m = fmaxf(fmaxf(a0, a1), fmaxf(a2, a3));
#pragma unroll
  for (int o = 1; o < 64; o <<= 1) m = fmaxf(m, __shfl_xor(m, o, 64));
  if (lane == 0) rmax[wv] = m;
  __syncthreads();
  m = fmaxf(fmaxf(rmax[0], rmax[1]), fmaxf(rmax[2], rmax[3]));
  float e0 = __expf(a0 - m), e1 = __expf(a1 - m);
  float e2 = __expf(a2 - m), e3 = __expf(a3 - m);
  float s = e0 + e1 + e2 + e3;
#pragma unroll
  for (int o = 1; o < 64; o <<= 1) s += __shfl_xor(s, o, 64);
  if (lane == 0) rsum[wv] = s;
  __syncthreads();
  s = rsum[0] + rsum[1] + rsum[2] + rsum[3];
  const float inv = 1.0f / s;
  union { u16 u[4]; uint2 p; } ob;
  ob.u[0] = f2bf(e0 * inv); ob.u[1] = f2bf(e1 * inv);
  ob.u[2] = f2bf(e2 * inv); ob.u[3] = f2bf(e3 * inv);
  *(uint2*)((u16*)sp + (t << 2)) = ob.p;   // all reads done before barriers
}

// ---------------------------------------------------------------------------
extern "C" void kernel_launch(void* const* d_in, const int* in_sizes, int n_in,
                              void* d_out, int out_size, void* d_ws, size_t ws_size,
                              hipStream_t stream) {
  const float* x  = (const float*)d_in[0];
  const float* qw = (const float*)d_in[1];
  const float* kw = (const float*)d_in[2];
  const float* vw = (const float*)d_in[3];
  float* out = (float*)d_out;
  char* ws = (char*)d_ws;

  // Workspace layout (bytes):
  //   q  bf16 [8][1024][4096]  @ 0          (64 MiB)
  //   k  bf16 [8][1024][4096]  @ 64 MiB     (64 MiB)
  //   vt bf16 [8][4096][1024]  @ 128 MiB    (64 MiB)
  //   score f32 [8][1024][1024] @ 192 MiB   (32 MiB; attn bf16 in-place)
  u16*  q     = (u16*)ws;
  u16*  k     = (u16*)(ws + 67108864);
  u16*  vt    = (u16*)(ws + 134217728);
  float* score = (float*)(ws + 201326592);

  dim3 cg(LL / 64, CC / 64, NB);
  dwconv_qkv<<<cg, 256, 0, stream>>>(x, qw, kw, vw, q, k, vt);

  // score[b] = q[b] (1024x4096) * k[b]^T -> [1024x1024] fp32
  dim3 g1(CC / 128, CC / 128, NB);
  gemm_nt<<<g1, 256, 0, stream>>>(q, LL, (size_t)CC * LL,
                                  k, LL, (size_t)CC * LL,
                                  score, CC, (size_t)CC * CC, LL);

  softmax_rows<<<NB * CC, 256, 0, stream>>>(score);

  // out[b] = attn[b] (1024x1024, bf16 rows strided 2048) * vt[b]^T (4096x1024)
  dim3 g2(LL / 128, CC / 128, NB);
  gemm_nt<<<g2, 256, 0, stream>>>((const u16*)score, 2048, (size_t)CC * 2048,
                                  vt, CC, (size_t)LL * CC,
                                  out, LL, (size_t)CC * LL, CC);
}

// Round 2
// 324.097 us; speedup vs baseline: 1.1641x; 1.1641x over previous
//
#include <hip/hip_runtime.h>
#include <hip/hip_bf16.h>

typedef unsigned short u16;
typedef __attribute__((ext_vector_type(8))) __bf16 bf16x8;
typedef __attribute__((ext_vector_type(4))) float f32x4;

#define CC 1024
#define LL 4096
#define NB 8

__device__ __forceinline__ u16 f2bf(float f) {
  union { float f; unsigned u; } v; v.f = f;
  unsigned u = v.u;
  return (u16)((u + 0x7fffu + ((u >> 16) & 1u)) >> 16);
}

__device__ __forceinline__ void gload_lds16(const void* g, void* l) {
  __builtin_amdgcn_global_load_lds(
      (const __attribute__((address_space(1))) void*)g,
      (__attribute__((address_space(3))) void*)l, 16, 0, 0);
}

// ---------------------------------------------------------------------------
// Fused depthwise conv (K=7, pad=3): q,k row-major [b,c,l] bf16, v transposed
// [b,l,c] bf16. Tile: 64 channels x 64 positions. x read directly from global
// into registers (float4); LDS used only for the v transpose.
// ---------------------------------------------------------------------------
__global__ __launch_bounds__(256) void dwconv_qkv(
    const float* __restrict__ x, const float* __restrict__ qw,
    const float* __restrict__ kw, const float* __restrict__ vw,
    u16* __restrict__ qo, u16* __restrict__ ko, u16* __restrict__ vto)
{
  __shared__ u16 vs[64][66];     // v tile transposed staging [l][c], odd dword stride
  const int t  = threadIdx.x;
  const int l0 = blockIdx.x << 6;
  const int c0 = blockIdx.y << 6;
  const int b  = blockIdx.z;
  const int cc  = t >> 2;          // channel within tile (0..63)
  const int li0 = (t & 3) << 4;    // 16 positions per thread
  const int c   = c0 + cc;
  const float* xr = x + ((size_t)(b * CC + c)) * LL;
  const int p0 = l0 + li0;         // first output position this thread owns

  // window [p0-3, p0+18]; load aligned [p0-4, p0+20) = 24 floats
  float xv[24];
  if (l0 != 0 && l0 != LL - 64) {
    const float4* base = (const float4*)(xr + p0 - 4);
#pragma unroll
    for (int j = 0; j < 6; ++j) {
      float4 f = base[j];
      xv[4 * j + 0] = f.x; xv[4 * j + 1] = f.y;
      xv[4 * j + 2] = f.z; xv[4 * j + 3] = f.w;
    }
  } else {
#pragma unroll
    for (int i = 0; i < 24; ++i) {
      int gl = p0 - 4 + i;
      xv[i] = ((unsigned)gl < (unsigned)LL) ? xr[gl] : 0.f;
    }
  }

  float wq[7], wk[7], wv[7];
#pragma unroll
  for (int j = 0; j < 7; ++j) {
    wq[j] = qw[c * 7 + j]; wk[j] = kw[c * 7 + j]; wv[j] = vw[c * 7 + j];
  }

  alignas(16) u16 qv[16], kv[16];
#pragma unroll
  for (int li = 0; li < 16; ++li) {
    float aq = 0.f, ak = 0.f, av = 0.f;
#pragma unroll
    for (int j = 0; j < 7; ++j) {
      float xf = xv[li + 1 + j];        // = x[p0 + li - 3 + j]
      aq = fmaf(xf, wq[j], aq);
      ak = fmaf(xf, wk[j], ak);
      av = fmaf(xf, wv[j], av);
    }
    qv[li] = f2bf(aq);
    kv[li] = f2bf(ak);
    vs[li0 + li][cc] = f2bf(av);
  }
  size_t qoff = ((size_t)(b * CC + c)) * LL + p0;
  *(uint4*)(qo + qoff)     = ((const uint4*)qv)[0];
  *(uint4*)(qo + qoff + 8) = ((const uint4*)qv)[1];
  *(uint4*)(ko + qoff)     = ((const uint4*)kv)[0];
  *(uint4*)(ko + qoff + 8) = ((const uint4*)kv)[1];

  __syncthreads();
  const int ll = t >> 2;
  const int cg = (t & 3) << 4;
  alignas(16) u16 vr[16];
#pragma unroll
  for (int j = 0; j < 16; ++j) vr[j] = vs[ll][cg + j];
  size_t voff = ((size_t)(b * LL + l0 + ll)) * CC + c0 + cg;
  *(uint4*)(vto + voff)     = ((const uint4*)vr)[0];
  *(uint4*)(vto + voff + 8) = ((const uint4*)vr)[1];
}

// ---------------------------------------------------------------------------
// NT bf16 GEMM: C[m][n] = sum_k A[m][k] * B[n][k]; A,B row-major K-contiguous.
// 128x128 tile, BK=64, 4 waves (2x2 of 64x64), mfma_f32_16x16x32_bf16.
// global_load_lds (16B) staging with XOR-swizzled source so swizzled
// ds_read_b128 fragment reads are ~conflict-free. m97-class structure.
// ---------------------------------------------------------------------------
__global__ __launch_bounds__(256) void gemm_nt(
    const u16* __restrict__ A, int lda, size_t sA,
    const u16* __restrict__ B, int ldb, size_t sB,
    float* __restrict__ C, int ldc, size_t sC, int K)
{
  __shared__ u16 As[8192];  // 128 x 64 bf16 (swizzled within rows)
  __shared__ u16 Bs[8192];
  const int t    = threadIdx.x;
  const int lane = t & 63, wave = t >> 6;
  const int WR = wave >> 1, WC = wave & 1;
  const int bm = blockIdx.y << 7, bn = blockIdx.x << 7;
  const size_t bz = blockIdx.z;
  const u16* Ab = A + bz * sA;
  const u16* Bb = B + bz * sB;

  // Staging addresses. Chunk = 1KB = 8 rows of 64 bf16; wave w owns chunks
  // 4w..4w+3. Lane l -> row = chunk*8 + (l>>3), source col block swizzled.
  const int srow = lane >> 3;                       // 0..7
  const int scol = ((lane & 7) ^ srow) << 3;        // swizzled elem col 0..56
  const u16* aSrc[4]; const u16* bSrc[4];
  u16* aDst[4]; u16* bDst[4];
#pragma unroll
  for (int i = 0; i < 4; ++i) {
    int chunk = wave * 4 + i;
    int row = chunk * 8 + srow;
    aSrc[i] = Ab + (size_t)(bm + row) * lda + scol;
    bSrc[i] = Bb + (size_t)(bn + row) * ldb + scol;
    aDst[i] = As + chunk * 512;
    bDst[i] = Bs + chunk * 512;
  }

  const int r15 = lane & 15;
  const int kq  = lane >> 4;   // 0..3
  const int swz = r15 & 7;

  f32x4 acc[4][4];
#pragma unroll
  for (int i = 0; i < 4; ++i)
#pragma unroll
    for (int j = 0; j < 4; ++j) acc[i][j] = f32x4{0.f, 0.f, 0.f, 0.f};

  int aOff[4], bOff[4];
#pragma unroll
  for (int mi = 0; mi < 4; ++mi) aOff[mi] = (WR * 64 + mi * 16 + r15) * 128;
#pragma unroll
  for (int ni = 0; ni < 4; ++ni) bOff[ni] = (WC * 64 + ni * 16 + r15) * 128;

  const int nk = K >> 6;
  for (int kt = 0; kt < nk; ++kt) {
    const int k0 = kt << 6;
#pragma unroll
    for (int i = 0; i < 4; ++i) {
      gload_lds16(aSrc[i] + k0, aDst[i]);
      gload_lds16(bSrc[i] + k0, bDst[i]);
    }
    __syncthreads();   // drains vmcnt before any wave reads LDS
#pragma unroll
    for (int ks = 0; ks < 2; ++ks) {
      const int u = (ks << 2) + kq;
      const int uo = (u ^ swz) << 4;
      bf16x8 af[4], bfr[4];
#pragma unroll
      for (int mi = 0; mi < 4; ++mi)
        af[mi] = *(const bf16x8*)((const char*)As + aOff[mi] + uo);
#pragma unroll
      for (int ni = 0; ni < 4; ++ni)
        bfr[ni] = *(const bf16x8*)((const char*)Bs + bOff[ni] + uo);
#pragma unroll
      for (int mi = 0; mi < 4; ++mi)
#pragma unroll
        for (int ni = 0; ni < 4; ++ni)
          acc[mi][ni] = __builtin_amdgcn_mfma_f32_16x16x32_bf16(
              af[mi], bfr[ni], acc[mi][ni], 0, 0, 0);
    }
    __syncthreads();   // before next-iter staging overwrites LDS
  }

  float* Cb = C + bz * sC;
  const int row0 = bm + WR * 64 + kq * 4;
  const int col0 = bn + WC * 64 + r15;
#pragma unroll
  for (int mi = 0; mi < 4; ++mi)
#pragma unroll
    for (int ni = 0; ni < 4; ++ni) {
      const int r   = row0 + mi * 16;
      const int col = col0 + ni * 16;
#pragma unroll
      for (int rr = 0; rr < 4; ++rr)
        Cb[(size_t)(r + rr) * ldc + col] = acc[mi][ni][rr];
    }
}

// ---------------------------------------------------------------------------
// Row softmax over fp32 [8192][1024] with 1/sqrt(C) scaling; writes bf16 attn
// in place at the start of each fp32 row (row stride stays 4096 B = 2048 u16).
// ---------------------------------------------------------------------------
__global__ __launch_bounds__(256) void softmax_rows(float* __restrict__ score)
{
  __shared__ float rmax[4], rsum[4];
  const int t = threadIdx.x;
  const int lane = t & 63, wv = t >> 6;
  float* sp = score + ((size_t)blockIdx.x << 10);
  float4 v = ((const float4*)sp)[t];
  const float scale = 0.03125f;   // 1/sqrt(1024)
  float a0 = v.x * scale, a1 = v.y * scale, a2 = v.z * scale, a3 = v.w * scale;
  float m = fmaxf(fmaxf(a0, a1), fmaxf(a2, a3));
#pragma unroll
  for (int o = 1; o < 64; o <<= 1) m = fmaxf(m, __shfl_xor(m, o, 64));
  if (lane == 0) rmax[wv] = m;
  __syncthreads();
  m = fmaxf(fmaxf(rmax[0], rmax[1]), fmaxf(rmax[2], rmax[3]));
  float e0 = __expf(a0 - m), e1 = __expf(a1 - m);
  float e2 = __expf(a2 - m), e3 = __expf(a3 - m);
  float s = e0 + e1 + e2 + e3;
#pragma unroll
  for (int o = 1; o < 64; o <<= 1) s += __shfl_xor(s, o, 64);
  if (lane == 0) rsum[wv] = s;
  __syncthreads();
  s = rsum[0] + rsum[1] + rsum[2] + rsum[3];
  const float inv = 1.0f / s;
  union { u16 u[4]; uint2 p; } ob;
  ob.u[0] = f2bf(e0 * inv); ob.u[1] = f2bf(e1 * inv);
  ob.u[2] = f2bf(e2 * inv); ob.u[3] = f2bf(e3 * inv);
  *(uint2*)((u16*)sp + (t << 2)) = ob.p;   // all reads done before barriers
}

// ---------------------------------------------------------------------------
extern "C" void kernel_launch(void* const* d_in, const int* in_sizes, int n_in,
                              void* d_out, int out_size, void* d_ws, size_t ws_size,
                              hipStream_t stream) {
  const float* x  = (const float*)d_in[0];
  const float* qw = (const float*)d_in[1];
  const float* kw = (const float*)d_in[2];
  const float* vw = (const float*)d_in[3];
  float* out = (float*)d_out;
  char* ws = (char*)d_ws;

  // Workspace layout (bytes):
  //   q  bf16 [8][1024][4096]  @ 0          (64 MiB)
  //   k  bf16 [8][1024][4096]  @ 64 MiB     (64 MiB)
  //   vt bf16 [8][4096][1024]  @ 128 MiB    (64 MiB)
  //   score f32 [8][1024][1024] @ 192 MiB   (32 MiB; attn bf16 in-place)
  u16*  q     = (u16*)ws;
  u16*  k     = (u16*)(ws + 67108864);
  u16*  vt    = (u16*)(ws + 134217728);
  float* score = (float*)(ws + 201326592);

  dim3 cg(LL / 64, CC / 64, NB);
  dwconv_qkv<<<cg, 256, 0, stream>>>(x, qw, kw, vw, q, k, vt);

  // score[b] = q[b] (1024x4096) * k[b]^T -> [1024x1024] fp32
  dim3 g1(CC / 128, CC / 128, NB);
  gemm_nt<<<g1, 256, 0, stream>>>(q, LL, (size_t)CC * LL,
                                  k, LL, (size_t)CC * LL,
                                  score, CC, (size_t)CC * CC, LL);

  softmax_rows<<<NB * CC, 256, 0, stream>>>(score);

  // out[b] = attn[b] (1024x1024, bf16 rows strided 2048) * vt[b]^T (4096x1024)
  dim3 g2(LL / 128, CC / 128, NB);
  gemm_nt<<<g2, 256, 0, stream>>>((const u16*)score, 2048, (size_t)CC * 2048,
                                  vt, CC, (size_t)LL * CC,
                                  out, LL, (size_t)CC * LL, CC);
}

// Round 3
// 297.572 us; speedup vs baseline: 1.2678x; 1.0891x over previous
//
#include <hip/hip_runtime.h>
#include <hip/hip_bf16.h>

typedef unsigned short u16;
typedef __attribute__((ext_vector_type(8))) __bf16 bf16x8;
typedef __attribute__((ext_vector_type(4))) float f32x4;

#define CC 1024
#define LL 4096
#define NB 8

#define VMCNT(n) asm volatile("s_waitcnt vmcnt(" #n ")" ::: "memory")
#define LGKM0()  asm volatile("s_waitcnt lgkmcnt(0)" ::: "memory")

__device__ __forceinline__ u16 f2bf(float f) {
  union { float f; unsigned u; } v; v.f = f;
  unsigned u = v.u;
  return (u16)((u + 0x7fffu + ((u >> 16) & 1u)) >> 16);
}

__device__ __forceinline__ void gload_lds16(const void* g, void* l) {
  __builtin_amdgcn_global_load_lds(
      (const __attribute__((address_space(1))) void*)g,
      (__attribute__((address_space(3))) void*)l, 16, 0, 0);
}

// ---------------------------------------------------------------------------
// Fused depthwise conv (K=7, pad=3): q,k row-major [b,c,l] bf16, v transposed
// [b,l,c] bf16. Tile: 64 channels x 64 positions; x read straight to regs.
// ---------------------------------------------------------------------------
__global__ __launch_bounds__(256) void dwconv_qkv(
    const float* __restrict__ x, const float* __restrict__ qw,
    const float* __restrict__ kw, const float* __restrict__ vw,
    u16* __restrict__ qo, u16* __restrict__ ko, u16* __restrict__ vto)
{
  __shared__ u16 vs[64][66];
  const int t  = threadIdx.x;
  const int l0 = blockIdx.x << 6;
  const int c0 = blockIdx.y << 6;
  const int b  = blockIdx.z;
  const int cc  = t >> 2;
  const int li0 = (t & 3) << 4;
  const int c   = c0 + cc;
  const float* xr = x + ((size_t)(b * CC + c)) * LL;
  const int p0 = l0 + li0;

  float xv[24];
  if (l0 != 0 && l0 != LL - 64) {
    const float4* base = (const float4*)(xr + p0 - 4);
#pragma unroll
    for (int j = 0; j < 6; ++j) {
      float4 f = base[j];
      xv[4 * j + 0] = f.x; xv[4 * j + 1] = f.y;
      xv[4 * j + 2] = f.z; xv[4 * j + 3] = f.w;
    }
  } else {
#pragma unroll
    for (int i = 0; i < 24; ++i) {
      int gl = p0 - 4 + i;
      xv[i] = ((unsigned)gl < (unsigned)LL) ? xr[gl] : 0.f;
    }
  }

  float wq[7], wk[7], wv[7];
#pragma unroll
  for (int j = 0; j < 7; ++j) {
    wq[j] = qw[c * 7 + j]; wk[j] = kw[c * 7 + j]; wv[j] = vw[c * 7 + j];
  }

  alignas(16) u16 qv[16], kv[16];
#pragma unroll
  for (int li = 0; li < 16; ++li) {
    float aq = 0.f, ak = 0.f, av = 0.f;
#pragma unroll
    for (int j = 0; j < 7; ++j) {
      float xf = xv[li + 1 + j];
      aq = fmaf(xf, wq[j], aq);
      ak = fmaf(xf, wk[j], ak);
      av = fmaf(xf, wv[j], av);
    }
    qv[li] = f2bf(aq);
    kv[li] = f2bf(ak);
    vs[li0 + li][cc] = f2bf(av);
  }
  size_t qoff = ((size_t)(b * CC + c)) * LL + p0;
  *(uint4*)(qo + qoff)     = ((const uint4*)qv)[0];
  *(uint4*)(qo + qoff + 8) = ((const uint4*)qv)[1];
  *(uint4*)(ko + qoff)     = ((const uint4*)kv)[0];
  *(uint4*)(ko + qoff + 8) = ((const uint4*)kv)[1];

  __syncthreads();
  const int ll = t >> 2;
  const int cg = (t & 3) << 4;
  alignas(16) u16 vr[16];
#pragma unroll
  for (int j = 0; j < 16; ++j) vr[j] = vs[ll][cg + j];
  size_t voff = ((size_t)(b * LL + l0 + ll)) * CC + c0 + cg;
  *(uint4*)(vto + voff)     = ((const uint4*)vr)[0];
  *(uint4*)(vto + voff + 8) = ((const uint4*)vr)[1];
}

// ---------------------------------------------------------------------------
// Deep-pipelined NT bf16 GEMM: C[m][n] = sum_k A[m][k]*B[n][k].
// BM=128 BN=256 BK=32, 512 threads = 8 waves (2Mx4N), 64x64 per wave.
// Triple-buffered LDS (72KB), prefetch distance 2, raw s_barrier + counted
// vmcnt(6) (T3/T4), XOR slot swizzle (T2), setprio around MFMA (T5).
// ---------------------------------------------------------------------------
__global__ __launch_bounds__(512, 2) void gemm_nt2(
    const u16* __restrict__ A, int lda, size_t sA,
    const u16* __restrict__ B, int ldb, size_t sB,
    float* __restrict__ C, int ldc, size_t sC, int K)
{
  // Per buffer: A 128x32 bf16 (8KB, 4096 u16) + B 256x32 (16KB, 8192 u16)
  __shared__ alignas(16) u16 lds[3 * 12288];
  const int t    = threadIdx.x;
  const int lane = t & 63, wave = t >> 6;
  const int wrow = wave >> 2, wcol = wave & 3;
  const int bm = blockIdx.y << 7, bn = blockIdx.x << 8;
  const size_t bz = blockIdx.z;
  const u16* Ab = A + bz * sA;
  const u16* Bb = B + bz * sB;

  // Staging: chunk = 16 rows x 64B. Lane L -> row L>>2, dest slot L&3; source
  // 16B-chunk = (L&3) ^ ((L>>2)&3) so that LDS[r][s] = G[r][s ^ (r&3)].
  const int crow  = lane >> 2;                       // row within chunk
  const int scol8 = (((lane & 3) ^ (crow & 3)) << 3); // source col (elems)
  const u16* aSrc  = Ab + (size_t)(bm + wave * 16 + crow) * lda + scol8;
  const u16* bSrc0 = Bb + (size_t)(bn + wave * 16 + crow) * ldb + scol8;
  const u16* bSrc1 = Bb + (size_t)(bn + (wave + 8) * 16 + crow) * ldb + scol8;

  const int r15 = lane & 15;
  const int kq  = lane >> 4;          // k-quarter 0..3 (8 elems each)
  // Fragment read byte offsets (swizzled): row*64 + ((kq ^ (r&3))<<4)
  int aOff[4], bOff[4];
#pragma unroll
  for (int m = 0; m < 4; ++m) {
    int r = wrow * 64 + m * 16 + r15;
    aOff[m] = r * 64 + (((kq ^ (r & 3))) << 4);
  }
#pragma unroll
  for (int n = 0; n < 4; ++n) {
    int r = wcol * 64 + n * 16 + r15;
    bOff[n] = r * 64 + (((kq ^ (r & 3))) << 4);
  }

  f32x4 acc[4][4];
#pragma unroll
  for (int i = 0; i < 4; ++i)
#pragma unroll
    for (int j = 0; j < 4; ++j) acc[i][j] = f32x4{0.f, 0.f, 0.f, 0.f};

  const int NT = K >> 5;

#define STAGE(kt, bi_)                                                  \
  do {                                                                  \
    u16* Abase = lds + (bi_) * 12288;                                   \
    u16* Bbase = Abase + 4096;                                          \
    const int k0_ = (kt) << 5;                                          \
    gload_lds16(aSrc  + k0_, Abase + (wave << 9));                      \
    gload_lds16(bSrc0 + k0_, Bbase + (wave << 9));                      \
    gload_lds16(bSrc1 + k0_, Bbase + ((wave + 8) << 9));                \
  } while (0)

#define COMPUTE(bi_)                                                    \
  do {                                                                  \
    const char* Al = (const char*)(lds + (bi_) * 12288);                \
    const char* Bl = Al + 8192;                                         \
    bf16x8 af[4], bfr[4];                                               \
    _Pragma("unroll")                                                   \
    for (int m = 0; m < 4; ++m) af[m] = *(const bf16x8*)(Al + aOff[m]); \
    _Pragma("unroll")                                                   \
    for (int n = 0; n < 4; ++n) bfr[n] = *(const bf16x8*)(Bl + bOff[n]);\
    LGKM0();                                                            \
    __builtin_amdgcn_sched_barrier(0);                                  \
    __builtin_amdgcn_s_setprio(1);                                      \
    _Pragma("unroll")                                                   \
    for (int m = 0; m < 4; ++m)                                         \
      _Pragma("unroll")                                                 \
      for (int n = 0; n < 4; ++n)                                       \
        acc[m][n] = __builtin_amdgcn_mfma_f32_16x16x32_bf16(            \
            af[m], bfr[n], acc[m][n], 0, 0, 0);                         \
    __builtin_amdgcn_s_setprio(0);                                      \
  } while (0)

  STAGE(0, 0);
  STAGE(1, 1);
  int bi = 0;
  for (int kt = 0; kt < NT; ++kt) {
    int pbi = bi + 2; if (pbi >= 3) pbi -= 3;
    if (kt + 2 < NT) STAGE(kt + 2, pbi);
    const int rem = NT - 1 - kt;
    if (rem >= 2)      VMCNT(6);   // own loads for kt landed; 2 tiles in flight
    else if (rem == 1) VMCNT(3);
    else               VMCNT(0);
    __builtin_amdgcn_s_barrier();  // all waves' loads for kt landed
    COMPUTE(bi);
    __builtin_amdgcn_s_barrier();  // all reads of buf bi done before overwrite
    bi = (bi == 2) ? 0 : bi + 1;
  }
#undef STAGE
#undef COMPUTE

  float* Cb = C + bz * sC;
  const int row0 = bm + wrow * 64 + kq * 4;
  const int col0 = bn + wcol * 64 + r15;
#pragma unroll
  for (int m = 0; m < 4; ++m)
#pragma unroll
    for (int n = 0; n < 4; ++n) {
      const int r   = row0 + m * 16;
      const int col = col0 + n * 16;
#pragma unroll
      for (int rr = 0; rr < 4; ++rr)
        Cb[(size_t)(r + rr) * ldc + col] = acc[m][n][rr];
    }
}

// ---------------------------------------------------------------------------
// Row softmax over fp32 [8192][1024] with 1/sqrt(C) scaling; writes bf16 attn
// in place at the start of each fp32 row (row stride 4096 B = 2048 u16).
// ---------------------------------------------------------------------------
__global__ __launch_bounds__(256) void softmax_rows(float* __restrict__ score)
{
  __shared__ float rmax[4], rsum[4];
  const int t = threadIdx.x;
  const int lane = t & 63, wv = t >> 6;
  float* sp = score + ((size_t)blockIdx.x << 10);
  float4 v = ((const float4*)sp)[t];
  const float scale = 0.03125f;   // 1/sqrt(1024)
  float a0 = v.x * scale, a1 = v.y * scale, a2 = v.z * scale, a3 = v.w * scale;
  float m = fmaxf(fmaxf(a0, a1), fmaxf(a2, a3));
#pragma unroll
  for (int o = 1; o < 64; o <<= 1) m = fmaxf(m, __shfl_xor(m, o, 64));
  if (lane == 0) rmax[wv] = m;
  __syncthreads();
  m = fmaxf(fmaxf(rmax[0], rmax[1]), fmaxf(rmax[2], rmax[3]));
  float e0 = __expf(a0 - m), e1 = __expf(a1 - m);
  float e2 = __expf(a2 - m), e3 = __expf(a3 - m);
  float s = e0 + e1 + e2 + e3;
#pragma unroll
  for (int o = 1; o < 64; o <<= 1) s += __shfl_xor(s, o, 64);
  if (lane == 0) rsum[wv] = s;
  __syncthreads();
  s = rsum[0] + rsum[1] + rsum[2] + rsum[3];
  const float inv = 1.0f / s;
  union { u16 u[4]; uint2 p; } ob;
  ob.u[0] = f2bf(e0 * inv); ob.u[1] = f2bf(e1 * inv);
  ob.u[2] = f2bf(e2 * inv); ob.u[3] = f2bf(e3 * inv);
  *(uint2*)((u16*)sp + (t << 2)) = ob.p;
}

// ---------------------------------------------------------------------------
extern "C" void kernel_launch(void* const* d_in, const int* in_sizes, int n_in,
                              void* d_out, int out_size, void* d_ws, size_t ws_size,
                              hipStream_t stream) {
  const float* x  = (const float*)d_in[0];
  const float* qw = (const float*)d_in[1];
  const float* kw = (const float*)d_in[2];
  const float* vw = (const float*)d_in[3];
  float* out = (float*)d_out;
  char* ws = (char*)d_ws;

  // Workspace: q bf16 @0 (64MB) | k bf16 @64MB | vt bf16 @128MB |
  //            score f32 [8][1024][1024] @192MB (attn bf16 in-place)
  u16*  q     = (u16*)ws;
  u16*  k     = (u16*)(ws + 67108864);
  u16*  vt    = (u16*)(ws + 134217728);
  float* score = (float*)(ws + 201326592);

  dim3 cg(LL / 64, CC / 64, NB);
  dwconv_qkv<<<cg, 256, 0, stream>>>(x, qw, kw, vw, q, k, vt);

  // score[b] = q[b] (1024x4096) * k[b]^T -> [1024x1024] fp32
  dim3 g1(CC / 256, CC / 128, NB);
  gemm_nt2<<<g1, 512, 0, stream>>>(q, LL, (size_t)CC * LL,
                                   k, LL, (size_t)CC * LL,
                                   score, CC, (size_t)CC * CC, LL);

  softmax_rows<<<NB * CC, 256, 0, stream>>>(score);

  // out[b] = attn[b] (1024x1024 bf16, rows strided 2048 u16) * vt[b]^T
  dim3 g2(LL / 256, CC / 128, NB);
  gemm_nt2<<<g2, 512, 0, stream>>>((const u16*)score, 2048, (size_t)CC * 2048,
                                   vt, CC, (size_t)LL * CC,
                                   out, LL, (size_t)CC * LL, CC);
}

// Round 4
// 286.851 us; speedup vs baseline: 1.3152x; 1.0374x over previous
//
#include <hip/hip_runtime.h>
#include <hip/hip_bf16.h>

typedef unsigned short u16;
typedef __attribute__((ext_vector_type(8))) __bf16 bf16x8;
typedef __attribute__((ext_vector_type(4))) float f32x4;

#define CC 1024
#define LL 4096
#define NB 8

#define VMCNT(n) asm volatile("s_waitcnt vmcnt(" #n ")" ::: "memory")
#define LGKM0()  asm volatile("s_waitcnt lgkmcnt(0)" ::: "memory")

__device__ __forceinline__ u16 f2bf(float f) {
  union { float f; unsigned u; } v; v.f = f;
  unsigned u = v.u;
  return (u16)((u + 0x7fffu + ((u >> 16) & 1u)) >> 16);
}

__device__ __forceinline__ void gload_lds16(const void* g, void* l) {
  __builtin_amdgcn_global_load_lds(
      (const __attribute__((address_space(1))) void*)g,
      (__attribute__((address_space(3))) void*)l, 16, 0, 0);
}

// ---------------------------------------------------------------------------
// Fused depthwise conv (K=7, pad=3): q,k row-major [b,c,l] bf16, v transposed
// [b,l,c] bf16. Tile: 64 channels x 64 positions; x read straight to regs.
// ---------------------------------------------------------------------------
__global__ __launch_bounds__(256) void dwconv_qkv(
    const float* __restrict__ x, const float* __restrict__ qw,
    const float* __restrict__ kw, const float* __restrict__ vw,
    u16* __restrict__ qo, u16* __restrict__ ko, u16* __restrict__ vto)
{
  __shared__ u16 vs[64][66];
  const int t  = threadIdx.x;
  const int l0 = blockIdx.x << 6;
  const int c0 = blockIdx.y << 6;
  const int b  = blockIdx.z;
  const int cc  = t >> 2;
  const int li0 = (t & 3) << 4;
  const int c   = c0 + cc;
  const float* xr = x + ((size_t)(b * CC + c)) * LL;
  const int p0 = l0 + li0;

  float xv[24];
  if (l0 != 0 && l0 != LL - 64) {
    const float4* base = (const float4*)(xr + p0 - 4);
#pragma unroll
    for (int j = 0; j < 6; ++j) {
      float4 f = base[j];
      xv[4 * j + 0] = f.x; xv[4 * j + 1] = f.y;
      xv[4 * j + 2] = f.z; xv[4 * j + 3] = f.w;
    }
  } else {
#pragma unroll
    for (int i = 0; i < 24; ++i) {
      int gl = p0 - 4 + i;
      xv[i] = ((unsigned)gl < (unsigned)LL) ? xr[gl] : 0.f;
    }
  }

  float wq[7], wk[7], wv[7];
#pragma unroll
  for (int j = 0; j < 7; ++j) {
    wq[j] = qw[c * 7 + j]; wk[j] = kw[c * 7 + j]; wv[j] = vw[c * 7 + j];
  }

  alignas(16) u16 qv[16], kv[16];
#pragma unroll
  for (int li = 0; li < 16; ++li) {
    float aq = 0.f, ak = 0.f, av = 0.f;
#pragma unroll
    for (int j = 0; j < 7; ++j) {
      float xf = xv[li + 1 + j];
      aq = fmaf(xf, wq[j], aq);
      ak = fmaf(xf, wk[j], ak);
      av = fmaf(xf, wv[j], av);
    }
    qv[li] = f2bf(aq);
    kv[li] = f2bf(ak);
    vs[li0 + li][cc] = f2bf(av);
  }
  size_t qoff = ((size_t)(b * CC + c)) * LL + p0;
  *(uint4*)(qo + qoff)     = ((const uint4*)qv)[0];
  *(uint4*)(qo + qoff + 8) = ((const uint4*)qv)[1];
  *(uint4*)(ko + qoff)     = ((const uint4*)kv)[0];
  *(uint4*)(ko + qoff + 8) = ((const uint4*)kv)[1];

  __syncthreads();
  const int ll = t >> 2;
  const int cg = (t & 3) << 4;
  alignas(16) u16 vr[16];
#pragma unroll
  for (int j = 0; j < 16; ++j) vr[j] = vs[ll][cg + j];
  size_t voff = ((size_t)(b * LL + l0 + ll)) * CC + c0 + cg;
  *(uint4*)(vto + voff)     = ((const uint4*)vr)[0];
  *(uint4*)(vto + voff + 8) = ((const uint4*)vr)[1];
}

// ---------------------------------------------------------------------------
// 256x256 NT bf16 GEMM, phase-interleaved pipeline.
// C[m][n] = sum_k A[m][k]*B[n][k]. 512 threads = 8 waves (2M x 4N); each wave
// owns 128x64 output (8x4 fragments of 16x16, mfma_f32_16x16x32_bf16).
// K consumed in 32-wide half-units; LDS = ring of 3 slots per operand
// (slot = 256 rows x 32 cols bf16 = 16KB; 96KB total), staged 2 half-units
// ahead via global_load_lds with pre-swizzled source (T2), counted vmcnt(4)
// once per half-unit (T3/T4), setprio around MFMA clusters (T5).
// Swizzle: LDS[r][s16] = G[r][s16 ^ ((r>>1)&3)], read s16 = kq ^ ((r>>1)&3)
//   -> position-in-128B = (r&1)*4 + s16 covers all 8 positions per 8 rows
//   -> <=2-way bank aliasing (free) on ds_read_b128.
// Optional split-K=2: blockIdx.z = batch*2+split; split 0 -> C0, 1 -> C1.
// ---------------------------------------------------------------------------
__global__ __launch_bounds__(512, 2) void gemm256(
    const u16* __restrict__ A, int lda, size_t sA,
    const u16* __restrict__ B, int ldb, size_t sB,
    float* __restrict__ C0, float* __restrict__ C1, int ldc, size_t sC,
    int K, int ksplit)
{
  __shared__ alignas(16) u16 As[3][8192];
  __shared__ alignas(16) u16 Bs[3][8192];
  const int t    = threadIdx.x;
  const int lane = t & 63, wave = t >> 6;
  const int wrow = wave >> 2, wcol = wave & 3;
  const int bm = blockIdx.y << 8, bn = blockIdx.x << 8;
  const int bz = blockIdx.z;
  const int batch = (ksplit == 2) ? (bz >> 1) : bz;
  const int split = (ksplit == 2) ? (bz & 1) : 0;
  const int Ks    = (ksplit == 2) ? (K >> 1) : K;
  const u16* Ab = A + (size_t)batch * sA + split * Ks;
  const u16* Bb = B + (size_t)batch * sB + split * Ks;

  // Staging: half-unit = 256 rows x 32 cols (16KB). Each wave: 2 gload_lds,
  // each covering 16 rows (1KB). Lane L -> row g*16 + (L>>2), dest 16B-slot
  // L&3 (linear DMA); source 16B-chunk pre-swizzled: (L&3) ^ ((L>>3)&3).
  const int sc8  = (((lane & 3) ^ ((lane >> 3) & 3)) << 3);
  const int srow = lane >> 2;
  const u16* aSrcB[2]; const u16* bSrcB[2];
  int gdst[2];
#pragma unroll
  for (int i = 0; i < 2; ++i) {
    int g = wave * 2 + i;                    // 16-row group 0..15
    aSrcB[i] = Ab + (size_t)(bm + g * 16 + srow) * lda + sc8;
    bSrcB[i] = Bb + (size_t)(bn + g * 16 + srow) * ldb + sc8;
    gdst[i]  = g * 512;                      // u16 offset of 16-row group
  }

  const int r15 = lane & 15, kq = lane >> 4;
  int aOff[8], bOff[4];
#pragma unroll
  for (int m = 0; m < 8; ++m) {
    int r = wrow * 128 + m * 16 + r15;
    aOff[m] = r * 64 + ((kq ^ ((r >> 1) & 3)) << 4);
  }
#pragma unroll
  for (int n = 0; n < 4; ++n) {
    int r = wcol * 64 + n * 16 + r15;
    bOff[n] = r * 64 + ((kq ^ ((r >> 1) & 3)) << 4);
  }

  f32x4 acc[8][4];
#pragma unroll
  for (int i = 0; i < 8; ++i)
#pragma unroll
    for (int j = 0; j < 4; ++j) acc[i][j] = f32x4{0.f, 0.f, 0.f, 0.f};

  const int H = Ks >> 5;   // half-units

#define STG_A(h2, s2) do {                                             \
    gload_lds16(aSrcB[0] + ((h2) << 5), &As[s2][gdst[0]]);             \
    gload_lds16(aSrcB[1] + ((h2) << 5), &As[s2][gdst[1]]); } while (0)
#define STG_B(h2, s2) do {                                             \
    gload_lds16(bSrcB[0] + ((h2) << 5), &Bs[s2][gdst[0]]);             \
    gload_lds16(bSrcB[1] + ((h2) << 5), &Bs[s2][gdst[1]]); } while (0)

  // Prologue: stage half-units 0,1 into slots 0,1; wait for unit 0.
  STG_A(0, 0); STG_B(0, 0);
  STG_A(1, 1); STG_B(1, 1);
  VMCNT(4);
  __builtin_amdgcn_s_barrier();

  int s = 0;
  for (int h = 0; h < H; ++h) {
    int s2 = s + 2; if (s2 >= 3) s2 -= 3;   // stage target (last read h-1)
    const char* Ap = (const char*)As[s];
    const char* Bp = (const char*)Bs[s];
    // ---- phase A: m-frags 0..3 ----
    bf16x8 af0[4], bfr[4];
#pragma unroll
    for (int m = 0; m < 4; ++m) af0[m] = *(const bf16x8*)(Ap + aOff[m]);
#pragma unroll
    for (int n = 0; n < 4; ++n) bfr[n] = *(const bf16x8*)(Bp + bOff[n]);
    if (h + 2 < H) STG_A(h + 2, s2);
    __builtin_amdgcn_s_barrier();
    LGKM0();
    __builtin_amdgcn_sched_barrier(0);
    __builtin_amdgcn_s_setprio(1);
#pragma unroll
    for (int m = 0; m < 4; ++m)
#pragma unroll
      for (int n = 0; n < 4; ++n)
        acc[m][n] = __builtin_amdgcn_mfma_f32_16x16x32_bf16(
            af0[m], bfr[n], acc[m][n], 0, 0, 0);
    __builtin_amdgcn_s_setprio(0);
    __builtin_amdgcn_s_barrier();
    // ---- phase B: m-frags 4..7 (B-frags reused in regs) ----
    bf16x8 af1[4];
#pragma unroll
    for (int m = 0; m < 4; ++m) af1[m] = *(const bf16x8*)(Ap + aOff[m + 4]);
    if (h + 2 < H) STG_B(h + 2, s2);
    if (h < H - 2) { VMCNT(4); } else { VMCNT(0); }
    __builtin_amdgcn_s_barrier();
    LGKM0();
    __builtin_amdgcn_sched_barrier(0);
    __builtin_amdgcn_s_setprio(1);
#pragma unroll
    for (int m = 0; m < 4; ++m)
#pragma unroll
      for (int n = 0; n < 4; ++n)
        acc[m + 4][n] = __builtin_amdgcn_mfma_f32_16x16x32_bf16(
            af1[m], bfr[n], acc[m + 4][n], 0, 0, 0);
    __builtin_amdgcn_s_setprio(0);
    __builtin_amdgcn_s_barrier();
    s = s + 1; if (s == 3) s = 0;
  }
#undef STG_A
#undef STG_B

  float* Cb = (split ? C1 : C0) + (size_t)batch * sC;
  const int row0 = bm + wrow * 128 + kq * 4;
  const int col0 = bn + wcol * 64 + r15;
#pragma unroll
  for (int m = 0; m < 8; ++m)
#pragma unroll
    for (int n = 0; n < 4; ++n) {
      const int r   = row0 + m * 16;
      const int col = col0 + n * 16;
#pragma unroll
      for (int rr = 0; rr < 4; ++rr)
        Cb[(size_t)(r + rr) * ldc + col] = acc[m][n][rr];
    }
}

// ---------------------------------------------------------------------------
// Row softmax over fp32 [8192][1024]: sums two split-K partials, scales by
// 1/sqrt(C); writes bf16 attn in place at the start of each fp32 score row
// (row stride stays 4096 B = 2048 u16).
// ---------------------------------------------------------------------------
__global__ __launch_bounds__(256) void softmax_rows(
    float* __restrict__ score, const float* __restrict__ part)
{
  __shared__ float rmax[4], rsum[4];
  const int t = threadIdx.x;
  const int lane = t & 63, wv = t >> 6;
  float* sp = score + ((size_t)blockIdx.x << 10);
  const float* pp = part + ((size_t)blockIdx.x << 10);
  float4 v = ((const float4*)sp)[t];
  float4 w = ((const float4*)pp)[t];
  const float scale = 0.03125f;   // 1/sqrt(1024)
  float a0 = (v.x + w.x) * scale, a1 = (v.y + w.y) * scale;
  float a2 = (v.z + w.z) * scale, a3 = (v.w + w.w) * scale;
  float m = fmaxf(fmaxf(a0, a1), fmaxf(a2, a3));
#pragma unroll
  for (int o = 1; o < 64; o <<= 1) m = fmaxf(m, __shfl_xor(m, o, 64));
  if (lane == 0) rmax[wv] = m;
  __syncthreads();
  m = fmaxf(fmaxf(rmax[0], rmax[1]), fmaxf(rmax[2], rmax[3]));
  float e0 = __expf(a0 - m), e1 = __expf(a1 - m);
  float e2 = __expf(a2 - m), e3 = __expf(a3 - m);
  float s = e0 + e1 + e2 + e3;
#pragma unroll
  for (int o = 1; o < 64; o <<= 1) s += __shfl_xor(s, o, 64);
  if (lane == 0) rsum[wv] = s;
  __syncthreads();
  s = rsum[0] + rsum[1] + rsum[2] + rsum[3];
  const float inv = 1.0f / s;
  union { u16 u[4]; uint2 p; } ob;
  ob.u[0] = f2bf(e0 * inv); ob.u[1] = f2bf(e1 * inv);
  ob.u[2] = f2bf(e2 * inv); ob.u[3] = f2bf(e3 * inv);
  *(uint2*)((u16*)sp + (t << 2)) = ob.p;
}

// ---------------------------------------------------------------------------
extern "C" void kernel_launch(void* const* d_in, const int* in_sizes, int n_in,
                              void* d_out, int out_size, void* d_ws, size_t ws_size,
                              hipStream_t stream) {
  const float* x  = (const float*)d_in[0];
  const float* qw = (const float*)d_in[1];
  const float* kw = (const float*)d_in[2];
  const float* vw = (const float*)d_in[3];
  float* out = (float*)d_out;
  char* ws = (char*)d_ws;

  // Workspace: q bf16 @0 (64MB) | k bf16 @64MB | vt bf16 @128MB |
  //            score f32 [8][1024][1024] @192MB (attn bf16 in-place).
  // Split-K partial (32MB fp32) lives in d_out (dead until GEMM2 overwrites).
  u16*  q      = (u16*)ws;
  u16*  k      = (u16*)(ws + 67108864);
  u16*  vt     = (u16*)(ws + 134217728);
  float* score = (float*)(ws + 201326592);
  float* part  = out;

  dim3 cg(LL / 64, CC / 64, NB);
  dwconv_qkv<<<cg, 256, 0, stream>>>(x, qw, kw, vw, q, k, vt);

  // score[b] = q[b] (1024x4096) * k[b]^T, split-K=2 -> score + part
  dim3 g1(CC / 256, CC / 256, NB * 2);
  gemm256<<<g1, 512, 0, stream>>>(q, LL, (size_t)CC * LL,
                                  k, LL, (size_t)CC * LL,
                                  score, part, CC, (size_t)CC * CC, LL, 2);

  softmax_rows<<<NB * CC, 256, 0, stream>>>(score, part);

  // out[b] = attn[b] (1024x1024 bf16, rows strided 2048 u16) * vt[b]^T
  dim3 g2(LL / 256, CC / 256, NB);
  gemm256<<<g2, 512, 0, stream>>>((const u16*)score, 2048, (size_t)CC * 2048,
                                  vt, CC, (size_t)LL * CC,
                                  out, nullptr, LL, (size_t)CC * LL, CC, 1);
}

// Round 5
// 251.464 us; speedup vs baseline: 1.5003x; 1.1407x over previous
//
#include <hip/hip_runtime.h>
#include <hip/hip_bf16.h>

typedef unsigned short u16;
typedef __attribute__((ext_vector_type(8))) __bf16 bf16x8;
typedef __attribute__((ext_vector_type(4))) float f32x4;

#define CC 1024
#define LL 4096
#define NB 8

#define VMCNT(n) asm volatile("s_waitcnt vmcnt(" #n ")" ::: "memory")
#define BAR()    asm volatile("s_barrier" ::: "memory")

__device__ __forceinline__ u16 f2bf(float f) {
  union { float f; unsigned u; } v; v.f = f;
  unsigned u = v.u;
  return (u16)((u + 0x7fffu + ((u >> 16) & 1u)) >> 16);
}

__device__ __forceinline__ void gload_lds16(const void* g, void* l) {
  __builtin_amdgcn_global_load_lds(
      (const __attribute__((address_space(1))) void*)g,
      (__attribute__((address_space(3))) void*)l, 16, 0, 0);
}

// ---------------------------------------------------------------------------
// Fused depthwise conv (K=7, pad=3): q,k row-major [b,c,l] bf16, v transposed
// [b,l,c] bf16. Tile: 64 channels x 64 positions; x read straight to regs.
// ---------------------------------------------------------------------------
__global__ __launch_bounds__(256) void dwconv_qkv(
    const float* __restrict__ x, const float* __restrict__ qw,
    const float* __restrict__ kw, const float* __restrict__ vw,
    u16* __restrict__ qo, u16* __restrict__ ko, u16* __restrict__ vto)
{
  __shared__ u16 vs[64][66];
  const int t  = threadIdx.x;
  const int l0 = blockIdx.x << 6;
  const int c0 = blockIdx.y << 6;
  const int b  = blockIdx.z;
  const int cc  = t >> 2;
  const int li0 = (t & 3) << 4;
  const int c   = c0 + cc;
  const float* xr = x + ((size_t)(b * CC + c)) * LL;
  const int p0 = l0 + li0;

  float xv[24];
  if (l0 != 0 && l0 != LL - 64) {
    const float4* base = (const float4*)(xr + p0 - 4);
#pragma unroll
    for (int j = 0; j < 6; ++j) {
      float4 f = base[j];
      xv[4 * j + 0] = f.x; xv[4 * j + 1] = f.y;
      xv[4 * j + 2] = f.z; xv[4 * j + 3] = f.w;
    }
  } else {
#pragma unroll
    for (int i = 0; i < 24; ++i) {
      int gl = p0 - 4 + i;
      xv[i] = ((unsigned)gl < (unsigned)LL) ? xr[gl] : 0.f;
    }
  }

  float wq[7], wk[7], wv[7];
#pragma unroll
  for (int j = 0; j < 7; ++j) {
    wq[j] = qw[c * 7 + j]; wk[j] = kw[c * 7 + j]; wv[j] = vw[c * 7 + j];
  }

  alignas(16) u16 qv[16], kv[16];
#pragma unroll
  for (int li = 0; li < 16; ++li) {
    float aq = 0.f, ak = 0.f, av = 0.f;
#pragma unroll
    for (int j = 0; j < 7; ++j) {
      float xf = xv[li + 1 + j];
      aq = fmaf(xf, wq[j], aq);
      ak = fmaf(xf, wk[j], ak);
      av = fmaf(xf, wv[j], av);
    }
    qv[li] = f2bf(aq);
    kv[li] = f2bf(ak);
    vs[li0 + li][cc] = f2bf(av);
  }
  size_t qoff = ((size_t)(b * CC + c)) * LL + p0;
  *(uint4*)(qo + qoff)     = ((const uint4*)qv)[0];
  *(uint4*)(qo + qoff + 8) = ((const uint4*)qv)[1];
  *(uint4*)(ko + qoff)     = ((const uint4*)kv)[0];
  *(uint4*)(ko + qoff + 8) = ((const uint4*)kv)[1];

  __syncthreads();
  const int ll = t >> 2;
  const int cg = (t & 3) << 4;
  alignas(16) u16 vr[16];
#pragma unroll
  for (int j = 0; j < 16; ++j) vr[j] = vs[ll][cg + j];
  size_t voff = ((size_t)(b * LL + l0 + ll)) * CC + c0 + cg;
  *(uint4*)(vto + voff)     = ((const uint4*)vr)[0];
  *(uint4*)(vto + voff + 8) = ((const uint4*)vr)[1];
}

// ---------------------------------------------------------------------------
// 256x256 NT bf16 GEMM, 4-phase/K-tile derived-waits pipeline (m201-class).
// C[m][n] = sum_k A[m][k]*B[n][k]. 512 thr = 8 waves (2M x 4N), 128x64/wave.
// BK=64; LDS = 2 dbuf x (A 256x64 + B 256x64) bf16 = 128 KB.
// Front-loaded reads: A(own half, k0+k1) at q1/q2, B k0 at q1, B k1 at q3.
//   -> A regions die at q2-end, B at q3-end.
// Stages: q1: B1(t+1)->other dbuf; q3: A0(t+2)->this dbuf; q4: A1,B0(t+2).
// One vmcnt(6) per K-tile (q4, pre-barrier): forces all of tile t+1 landed
// (FIFO: 8 older loads forced, leaves A0/A1/B0(t+2)=6). Tail: vmcnt(0).
// Barriers (raw s_barrier, no drain) at q2/q3/q4-end only.
// Swizzle: LDS[r][c16] = G[r][c16 ^ (r&7)]; read c16 = (s*4+kq)^(r15&7)
//   -> 2-way max bank aliasing (free) on ds_read_b128.
// mapmode: XCD-aware block decode (T1).
// ---------------------------------------------------------------------------
__global__ __launch_bounds__(512, 2) void gemm256p(
    const u16* __restrict__ A, int lda, size_t sA,
    const u16* __restrict__ B, int ldb, size_t sB,
    float* __restrict__ C0, float* __restrict__ C1, int ldc, size_t sC,
    int K, int ksplit, int mapmode)
{
  __shared__ alignas(16) u16 lds[65536];   // 128 KB
  const int t    = threadIdx.x;
  const int lane = t & 63, wave = t >> 6;
  const int wrow = wave >> 2, wcol = wave & 3;
  int bx, by, z;
  if (mapmode == 0) {        // GEMM1: 256 blocks; XCD x <- batch-splits {x,x+8}
    int wg = blockIdx.x; z = wg & 15; int r = wg >> 4; bx = r & 3; by = r >> 2;
  } else {                   // GEMM2: 512 blocks; XCD x <- batch x, y-fastest
    int wg = blockIdx.x; z = wg & 7; by = (wg >> 3) & 3; bx = wg >> 5;
  }
  const int bm = by << 8, bn = bx << 8;
  const int batch = (ksplit == 2) ? (z >> 1) : z;
  const int split = (ksplit == 2) ? (z & 1) : 0;
  const int Ks    = (ksplit == 2) ? (K >> 1) : K;
  const u16* Ab = A + (size_t)batch * sA + (size_t)split * Ks;
  const u16* Bb = B + (size_t)batch * sB + (size_t)split * Ks;

  // --- staging pointers: chunk c = wave*2+i covers 8 rows x 128B
  const int srow = lane >> 3;
  const int scol = ((lane & 7) ^ srow) << 3;   // pre-swizzled source col
  const u16* pA[2][2]; const u16* pB[2][2];    // [half][i]
  int dstOff[2];
#pragma unroll
  for (int i = 0; i < 2; ++i) {
    int c = wave * 2 + i;
    dstOff[i] = c * 1024 + lane * 16;          // byte offset within 16KB half
    pA[0][i] = Ab + (size_t)(bm + c * 8 + srow) * lda + scol;
    pA[1][i] = pA[0][i] + (size_t)128 * lda;
    pB[0][i] = Bb + (size_t)(bn + c * 8 + srow) * ldb + scol;
    pB[1][i] = pB[0][i] + (size_t)128 * ldb;
  }
  // dbuf d byte base = d*65536; A half h at h*16384; B at 32768 + h*16384.

#define STGH(P, h, base, koff)                                            \
  do {                                                                    \
    gload_lds16(P[h][0] + (koff), (char*)lds + (base) + dstOff[0]);       \
    gload_lds16(P[h][1] + (koff), (char*)lds + (base) + dstOff[1]);       \
  } while (0)

  // --- fragment read offsets
  const int r15 = lane & 15, kq = lane >> 4, swz = r15 & 7;
  int rowA[8], rowB[4], colK[2];
#pragma unroll
  for (int m = 0; m < 8; ++m) rowA[m] = (wrow * 128 + m * 16 + r15) * 128;
#pragma unroll
  for (int n = 0; n < 4; ++n) rowB[n] = 32768 + (wcol * 64 + n * 16 + r15) * 128;
#pragma unroll
  for (int s = 0; s < 2; ++s) colK[s] = (((s * 4 + kq) ^ swz)) << 4;

  f32x4 acc[8][4];
#pragma unroll
  for (int i = 0; i < 8; ++i)
#pragma unroll
    for (int j = 0; j < 4; ++j) acc[i][j] = f32x4{0.f, 0.f, 0.f, 0.f};

  const int NT = Ks >> 6;

  // --- prologue: tile0 -> dbuf0 (all), tile1 -> dbuf1 (A0,A1,B0)
  STGH(pA, 0, 0, 0);            STGH(pA, 1, 16384, 0);
  STGH(pB, 0, 32768, 0);        STGH(pB, 1, 49152, 0);
  STGH(pA, 0, 65536 + 0, 64);   STGH(pA, 1, 65536 + 16384, 64);
  STGH(pB, 0, 65536 + 32768, 64);
  VMCNT(6);
  BAR();

  const char* L = (const char*)lds;
  for (int tt = 0; tt < NT; ++tt) {
    const int d = tt & 1;
    const int dbase = d << 16, sbase = (d ^ 1) << 16;
    const int kN1 = (tt + 1) << 6, kN2 = (tt + 2) << 6;
    // ---- q1: A own m0-3 (k0,k1) + B k0; stage B1(t+1); MFMA (m0-3, k0)
    bf16x8 a0[4], aK1a[4], b0[4];
#pragma unroll
    for (int m = 0; m < 4; ++m) {
      a0[m]   = *(const bf16x8*)(L + dbase + rowA[m] + colK[0]);
      aK1a[m] = *(const bf16x8*)(L + dbase + rowA[m] + colK[1]);
    }
#pragma unroll
    for (int n = 0; n < 4; ++n) b0[n] = *(const bf16x8*)(L + dbase + rowB[n] + colK[0]);
    if (tt + 1 < NT) STGH(pB, 1, sbase + 49152, kN1);
    __builtin_amdgcn_s_setprio(1);
#pragma unroll
    for (int m = 0; m < 4; ++m)
#pragma unroll
      for (int n = 0; n < 4; ++n)
        acc[m][n] = __builtin_amdgcn_mfma_f32_16x16x32_bf16(a0[m], b0[n], acc[m][n], 0, 0, 0);
    __builtin_amdgcn_s_setprio(0);
    // ---- q2: A own m4-7 (k0,k1); MFMA (m4-7, k0)
    bf16x8 a4[4], aK1b[4];
#pragma unroll
    for (int m = 0; m < 4; ++m) {
      a4[m]   = *(const bf16x8*)(L + dbase + rowA[m + 4] + colK[0]);
      aK1b[m] = *(const bf16x8*)(L + dbase + rowA[m + 4] + colK[1]);
    }
    __builtin_amdgcn_s_setprio(1);
#pragma unroll
    for (int m = 0; m < 4; ++m)
#pragma unroll
      for (int n = 0; n < 4; ++n)
        acc[m + 4][n] = __builtin_amdgcn_mfma_f32_16x16x32_bf16(a4[m], b0[n], acc[m + 4][n], 0, 0, 0);
    __builtin_amdgcn_s_setprio(0);
    BAR();                     // all A(t) reads done -> q3 stage may overwrite
    // ---- q3: B k1; stage A0(t+2) into THIS dbuf; MFMA (m0-3, k1)
    bf16x8 b1[4];
#pragma unroll
    for (int n = 0; n < 4; ++n) b1[n] = *(const bf16x8*)(L + dbase + rowB[n] + colK[1]);
    if (tt + 2 < NT) STGH(pA, 0, dbase + 0, kN2);
    __builtin_amdgcn_s_setprio(1);
#pragma unroll
    for (int m = 0; m < 4; ++m)
#pragma unroll
      for (int n = 0; n < 4; ++n)
        acc[m][n] = __builtin_amdgcn_mfma_f32_16x16x32_bf16(aK1a[m], b1[n], acc[m][n], 0, 0, 0);
    __builtin_amdgcn_s_setprio(0);
    BAR();                     // all B(t) reads done -> q4 stages safe
    // ---- q4: stage A1,B0(t+2); MFMA (m4-7, k1); vmcnt; barrier
    if (tt + 2 < NT) { STGH(pA, 1, dbase + 16384, kN2); STGH(pB, 0, dbase + 32768, kN2); }
    __builtin_amdgcn_s_setprio(1);
#pragma unroll
    for (int m = 0; m < 4; ++m)
#pragma unroll
      for (int n = 0; n < 4; ++n)
        acc[m + 4][n] = __builtin_amdgcn_mfma_f32_16x16x32_bf16(aK1b[m], b1[n], acc[m + 4][n], 0, 0, 0);
    __builtin_amdgcn_s_setprio(0);
    if (tt < NT - 2) { VMCNT(6); } else { VMCNT(0); }
    BAR();                     // tile t+1 fully landed before next q1 reads
  }
#undef STGH

  float* Cb = (split ? C1 : C0) + (size_t)batch * sC;
  const int row0 = bm + wrow * 128 + kq * 4;
  const int col0 = bn + wcol * 64 + r15;
#pragma unroll
  for (int m = 0; m < 8; ++m)
#pragma unroll
    for (int n = 0; n < 4; ++n) {
      const int r   = row0 + m * 16;
      const int col = col0 + n * 16;
#pragma unroll
      for (int rr = 0; rr < 4; ++rr)
        Cb[(size_t)(r + rr) * ldc + col] = acc[m][n][rr];
    }
}

// ---------------------------------------------------------------------------
// Row softmax over fp32 [8192][1024]: sums split-K partials, scales 1/sqrt(C),
// writes bf16 attn in place (row stride stays 4096 B = 2048 u16).
// ---------------------------------------------------------------------------
__global__ __launch_bounds__(256) void softmax_rows(
    float* __restrict__ score, const float* __restrict__ part)
{
  __shared__ float rmax[4], rsum[4];
  const int t = threadIdx.x;
  const int lane = t & 63, wv = t >> 6;
  float* sp = score + ((size_t)blockIdx.x << 10);
  const float* pp = part + ((size_t)blockIdx.x << 10);
  float4 v = ((const float4*)sp)[t];
  float4 w = ((const float4*)pp)[t];
  const float scale = 0.03125f;   // 1/sqrt(1024)
  float a0 = (v.x + w.x) * scale, a1 = (v.y + w.y) * scale;
  float a2 = (v.z + w.z) * scale, a3 = (v.w + w.w) * scale;
  float m = fmaxf(fmaxf(a0, a1), fmaxf(a2, a3));
#pragma unroll
  for (int o = 1; o < 64; o <<= 1) m = fmaxf(m, __shfl_xor(m, o, 64));
  if (lane == 0) rmax[wv] = m;
  __syncthreads();
  m = fmaxf(fmaxf(rmax[0], rmax[1]), fmaxf(rmax[2], rmax[3]));
  float e0 = __expf(a0 - m), e1 = __expf(a1 - m);
  float e2 = __expf(a2 - m), e3 = __expf(a3 - m);
  float s = e0 + e1 + e2 + e3;
#pragma unroll
  for (int o = 1; o < 64; o <<= 1) s += __shfl_xor(s, o, 64);
  if (lane == 0) rsum[wv] = s;
  __syncthreads();
  s = rsum[0] + rsum[1] + rsum[2] + rsum[3];
  const float inv = 1.0f / s;
  union { u16 u[4]; uint2 p; } ob;
  ob.u[0] = f2bf(e0 * inv); ob.u[1] = f2bf(e1 * inv);
  ob.u[2] = f2bf(e2 * inv); ob.u[3] = f2bf(e3 * inv);
  *(uint2*)((u16*)sp + (t << 2)) = ob.p;
}

// ---------------------------------------------------------------------------
extern "C" void kernel_launch(void* const* d_in, const int* in_sizes, int n_in,
                              void* d_out, int out_size, void* d_ws, size_t ws_size,
                              hipStream_t stream) {
  const float* x  = (const float*)d_in[0];
  const float* qw = (const float*)d_in[1];
  const float* kw = (const float*)d_in[2];
  const float* vw = (const float*)d_in[3];
  float* out = (float*)d_out;
  char* ws = (char*)d_ws;

  // Workspace: q bf16 @0 (64MB) | k bf16 @64MB | vt bf16 @128MB |
  //            score f32 [8][1024][1024] @192MB (attn bf16 in-place).
  // Split-K partial (32MB fp32) lives in d_out (dead until GEMM2 overwrites).
  u16*  q      = (u16*)ws;
  u16*  k      = (u16*)(ws + 67108864);
  u16*  vt     = (u16*)(ws + 134217728);
  float* score = (float*)(ws + 201326592);
  float* part  = out;

  dim3 cg(LL / 64, CC / 64, NB);
  dwconv_qkv<<<cg, 256, 0, stream>>>(x, qw, kw, vw, q, k, vt);

  // score[b] = q[b] (1024x4096) * k[b]^T, split-K=2 -> score + part
  gemm256p<<<dim3(256), 512, 0, stream>>>(q, LL, (size_t)CC * LL,
                                          k, LL, (size_t)CC * LL,
                                          score, part, CC, (size_t)CC * CC,
                                          LL, 2, 0);

  softmax_rows<<<NB * CC, 256, 0, stream>>>(score, part);

  // out[b] = attn[b] (1024x1024 bf16, rows strided 2048 u16) * vt[b]^T
  gemm256p<<<dim3(512), 512, 0, stream>>>((const u16*)score, 2048, (size_t)CC * 2048,
                                          vt, CC, (size_t)LL * CC,
                                          out, nullptr, LL, (size_t)CC * LL,
                                          CC, 1, 1);
}